// Round 5
// baseline (375.013 us; speedup 1.0000x reference)
//
#include <hip/hip_runtime.h>
#include <hip/hip_bf16.h>

// Cross-attention B=8, S_ENC=2048, S_DEC=1024, D=512, U=512.
// R5: fused flash-attention kernel (score+softmax+PV in one launch) replaces
// the S (134 MB) and P (67 MB) round-trips. fp16 MFMA, fp32 logits/stats/O.
// Projections/converts unchanged from R4.
//
// ws: qh [0,8M) fp16[8192][512] | kh [8M,24M) fp16[16384][512] |
//     vt [32M,48M) fp16[8][512][2048] | dech @48M | Wt @56M | ench @112M

typedef __attribute__((ext_vector_type(8))) _Float16 f16x8;
typedef __attribute__((ext_vector_type(4))) _Float16 f16x4;
typedef __attribute__((ext_vector_type(4))) float f32x4;

#define MFMA16(a, b, c) __builtin_amdgcn_mfma_f32_16x16x32_f16(a, b, c, 0, 0, 0)
#define L2E 1.44269504088896f

__device__ __forceinline__ void glds16(const void* g, void* l) {
    __builtin_amdgcn_global_load_lds(
        (const __attribute__((address_space(1))) void*)g,
        (__attribute__((address_space(3))) void*)l, 16, 0, 0);
}

// ------------------------- fused flash attention -------------------------
// Block: 512 thr (8 waves). q-tile = 32 rows. Chunk = 64 enc cols, d-sub 128.
// S waves: qg=w&1 (16 q-rows), kg=w>>1 (16 kc-cols). PV: wave owns u-slab w*64.
// K/q LDS rows XOR-swizzled in 16B chunks (chunk ^= row&7) -> 2-way-free frag reads.
// Stats (ms), chmax/chsum double-buffered in LDS; P chunk [32][72] fp16.
#define QS_OFF 0
#define KS_OFF 32768
#define PS_OFF 65536
#define MS_OFF 70144
#define CHMAX_OFF 70400
#define CHSUM_OFF 71424
#define SMEM_SZ 72448

__global__ __launch_bounds__(512, 4) void attn_kernel(
    const _Float16* __restrict__ qh, const _Float16* __restrict__ kh,
    const _Float16* __restrict__ vt, float* __restrict__ out) {
    __shared__ __align__(16) char smem[SMEM_SZ];
    const int tid = threadIdx.x;
    const int wave = tid >> 6, lane = tid & 63;
    const int quad = lane >> 4, m16 = lane & 15;
    const int qg = wave & 1, kg = wave >> 1;
    const int uw = wave * 64;
    const int z = blockIdx.x & 7;          // batch -> XCD pinning (i%8 heuristic)
    const int qt = blockIdx.x >> 3;
    const int g0 = z * 1024 + qt * 32;     // global q row base

    // ---- prologue: stage q tile (swizzled), init ms[0], stage K tile 0 ----
    {
        const int r8w = wave;  // row&7 == wave for all q-stage rounds
#pragma unroll
        for (int r = 0; r < 4; ++r)
            glds16(qh + (size_t)(g0 + r * 8 + wave) * 512 + (lane ^ r8w) * 8,
                   smem + QS_OFF + r * 8192 + wave * 1024);
    }
    if (tid < 32) *(float*)(smem + MS_OFF + tid * 4) = -1e30f;

    const int krl = tid >> 4;  // 0..31
    const _Float16* khp = kh + (size_t)(z * 2048 + krl) * 512 + (m16 ^ (krl & 7)) * 8;
    auto stageK = [&](int tt2) {
        const int ci2 = tt2 >> 2, ds2 = tt2 & 3, buf2 = tt2 & 1;
#pragma unroll
        for (int r = 0; r < 2; ++r)
            glds16(khp + ci2 * 32768 + r * 16384 + ds2 * 128,
                   smem + KS_OFF + buf2 * 16384 + r * 8192 + wave * 1024);
    };
    stageK(0);

    f32x4 O[2][4];
#pragma unroll
    for (int mt = 0; mt < 2; ++mt)
#pragma unroll
        for (int nt = 0; nt < 4; ++nt) O[mt][nt] = (f32x4){0.f, 0.f, 0.f, 0.f};
    float l_[2][4] = {{0.f, 0.f, 0.f, 0.f}, {0.f, 0.f, 0.f, 0.f}};
    f32x4 sacc;

    const int sw = m16 & 7;
    const int qrow_base = QS_OFF + (qg * 16 + m16) * 1024;
    const int krow_base = KS_OFF + (kg * 16 + m16) * 256;
    const _Float16* vbase = vt + (size_t)(z * 512 + uw + m16) * 2048 + quad * 8;

    auto S_sub = [&](int buf, int sub) {
#pragma unroll
        for (int ks = 0; ks < 4; ++ks) {
            f16x8 af = *(const f16x8*)(smem + qrow_base +
                                       (((sub * 16 + ks * 4 + quad) ^ sw) << 4));
            f16x8 bf = *(const f16x8*)(smem + krow_base + buf * 16384 +
                                       (((ks * 4 + quad) ^ sw) << 4));
            sacc = MFMA16(af, bf, sacc);
        }
    };
    auto PV_piece = [&](int cip, int nt) {
#pragma unroll
        for (int kk = 0; kk < 2; ++kk) {
            f16x8 vf = *(const f16x8*)(vbase + (size_t)nt * 16 * 2048 + cip * 64 + kk * 32);
#pragma unroll
            for (int mt = 0; mt < 2; ++mt) {
                f16x8 pf = *(const f16x8*)(smem + PS_OFF + (mt * 16 + m16) * 144 +
                                           kk * 64 + quad * 16);
                O[mt][nt] = MFMA16(pf, vf, O[mt][nt]);
            }
        }
    };
    // softmax segment for chunk cip (uses sacc of chunk cip). Writes Ps,
    // chsum[b], ms[b^1]; rescales O by alpha.
    auto segment = [&](int cip) {
        const int b = cip & 1;
        const int row = lane & 31;
        float cm = *(const float*)(smem + CHMAX_OFF + b * 512 + row * 4);
#pragma unroll
        for (int k2 = 1; k2 < 4; ++k2)
            cm = fmaxf(cm, *(const float*)(smem + CHMAX_OFF + b * 512 + k2 * 128 + row * 4));
        float mo = *(const float*)(smem + MS_OFF + b * 128 + row * 4);
        float mn = fmaxf(mo, cm);
        float al = exp2f((mo - mn) * L2E);
        if (wave == 0 && lane < 32) *(float*)(smem + MS_OFF + (b ^ 1) * 128 + row * 4) = mn;
        float p[4];
#pragma unroll
        for (int r = 0; r < 4; ++r) {
            float mnr = __shfl(mn, qg * 16 + quad * 4 + r);
            p[r] = exp2f((sacc[r] - mnr) * L2E);
            *(_Float16*)(smem + PS_OFF + (qg * 16 + quad * 4 + r) * 144 +
                         (kg * 16 + m16) * 2) = (_Float16)p[r];
        }
        float ps[4] = {p[0], p[1], p[2], p[3]};
#pragma unroll
        for (int mask = 1; mask < 16; mask <<= 1)
#pragma unroll
            for (int r = 0; r < 4; ++r) ps[r] += __shfl_xor(ps[r], mask);
        if (m16 == 0) {
#pragma unroll
            for (int r = 0; r < 4; ++r)
                *(float*)(smem + CHSUM_OFF + b * 512 + kg * 128 +
                          (qg * 16 + quad * 4 + r) * 4) = ps[r];
        }
#pragma unroll
        for (int mt = 0; mt < 2; ++mt)
#pragma unroll
            for (int rr = 0; rr < 4; ++rr) {
                float a2 = __shfl(al, mt * 16 + quad * 4 + rr);
#pragma unroll
                for (int nt = 0; nt < 4; ++nt) O[mt][nt][rr] *= a2;
            }
    };
    auto l_update = [&](int cip) {
        const int b = cip & 1;
        const int row = lane & 31;
        float cs = *(const float*)(smem + CHSUM_OFF + b * 512 + row * 4);
#pragma unroll
        for (int k2 = 1; k2 < 4; ++k2)
            cs += *(const float*)(smem + CHSUM_OFF + b * 512 + k2 * 128 + row * 4);
        float alo = exp2f((*(const float*)(smem + MS_OFF + b * 128 + row * 4) -
                           *(const float*)(smem + MS_OFF + (b ^ 1) * 128 + row * 4)) * L2E);
#pragma unroll
        for (int mt = 0; mt < 2; ++mt)
#pragma unroll
            for (int rr = 0; rr < 4; ++rr) {
                int orow = mt * 16 + quad * 4 + rr;
                l_[mt][rr] = l_[mt][rr] * __shfl(alo, orow) + __shfl(cs, orow);
            }
    };

    for (int ci = 0; ci < 32; ++ci) {
        // --- sub 0 (carries the softmax segment of chunk ci-1) ---
        __syncthreads();  // K tile 4ci ready; chmax of ci-1 visible
        if (ci > 0) segment(ci - 1);
        __syncthreads();  // Ps / chsum / ms visible
        if (ci > 0) l_update(ci - 1);
        sacc = (f32x4){0.f, 0.f, 0.f, 0.f};
        stageK(4 * ci + 1);
        S_sub(0 /*buf: (4ci)&1=0*/, 0);
        if (ci > 0) PV_piece(ci - 1, 0);
        // --- subs 1..3 ---
#pragma unroll
        for (int sub = 1; sub < 4; ++sub) {
            const int tt = 4 * ci + sub;
            __syncthreads();
            if (tt + 1 < 128) stageK(tt + 1);
            S_sub(tt & 1, sub);
            if (ci > 0) PV_piece(ci - 1, sub);
        }
        // --- rowmax + chmax write for chunk ci ---
        f32x4 tm = sacc;
#pragma unroll
        for (int mask = 1; mask < 16; mask <<= 1)
#pragma unroll
            for (int r = 0; r < 4; ++r) tm[r] = fmaxf(tm[r], __shfl_xor(tm[r], mask));
        if (m16 == 0) {
#pragma unroll
            for (int r = 0; r < 4; ++r)
                *(float*)(smem + CHMAX_OFF + (ci & 1) * 512 + kg * 128 +
                          (qg * 16 + quad * 4 + r) * 4) = tm[r];
        }
    }
    // --- drain: chunk 31 ---
    __syncthreads();
    segment(31);
    __syncthreads();
    l_update(31);
#pragma unroll
    for (int nt = 0; nt < 4; ++nt) PV_piece(31, nt);
    // --- epilogue: normalize + store ---
#pragma unroll
    for (int mt = 0; mt < 2; ++mt)
#pragma unroll
        for (int rr = 0; rr < 4; ++rr) {
            float linv = 1.0f / l_[mt][rr];
            int grow = g0 + mt * 16 + quad * 4 + rr;
#pragma unroll
            for (int nt = 0; nt < 4; ++nt)
                out[(size_t)grow * 512 + uw + nt * 16 + m16] = O[mt][nt][rr] * linv;
        }
}

// ------------------------- conversion + projections (unchanged R4) -------------------------

__global__ __launch_bounds__(256) void convert_f16(const float* __restrict__ x,
                                                   _Float16* __restrict__ o) {
    size_t i = ((size_t)blockIdx.x * 256 + threadIdx.x) * 8;
    float4 a0 = *(const float4*)(x + i);
    float4 a1 = *(const float4*)(x + i + 4);
    float v[8] = {a0.x, a0.y, a0.z, a0.w, a1.x, a1.y, a1.z, a1.w};
    f16x8 h;
#pragma unroll
    for (int j = 0; j < 8; ++j) h[j] = (_Float16)v[j];
    *(f16x8*)(o + i) = h;
}

__global__ __launch_bounds__(256) void wtrans_kernel(const float* __restrict__ Wq,
                                                     const float* __restrict__ Wk,
                                                     const float* __restrict__ Wv,
                                                     _Float16* __restrict__ planes) {
    const float* W = blockIdx.z == 0 ? Wq : (blockIdx.z == 1 ? Wk : Wv);
    _Float16* ot = planes + (size_t)blockIdx.z * 262144;
    __shared__ float T[64][65];
    const int d0 = blockIdx.y * 64, u0 = blockIdx.x * 64;
    const int tr = threadIdx.x >> 4, tc = (threadIdx.x & 15) * 4;
#pragma unroll
    for (int j = 0; j < 4; ++j) {
        float4 vv = *(const float4*)(W + (size_t)(d0 + tr + j * 16) * 512 + u0 + tc);
        T[tr + j * 16][tc + 0] = vv.x;
        T[tr + j * 16][tc + 1] = vv.y;
        T[tr + j * 16][tc + 2] = vv.z;
        T[tr + j * 16][tc + 3] = vv.w;
    }
    __syncthreads();
#pragma unroll
    for (int j = 0; j < 4; ++j) {
        int ul = tr + j * 16;
        f16x4 h;
#pragma unroll
        for (int i = 0; i < 4; ++i) h[i] = (_Float16)T[tc + i][ul];
        *(f16x4*)(ot + (size_t)(u0 + ul) * 512 + d0 + tc) = h;
    }
}

// BM x 128 tile GEMM (fp16, dbuf K-loop). OUT: 0 = fp16 C, 1 = transposed fp16 vt.
template <int BM, int OUT>
__global__ __launch_bounds__(256) void gemm_kernel(
    const _Float16* __restrict__ A, const _Float16* __restrict__ B,
    void* __restrict__ O1,
    int lda, int ldb, int K, int a_row_batch, long b_batch, int ldo) {
    constexpr int BUFSZ = BM * 64 + 8192;
    constexpr int MT = BM / 32;
    constexpr int JA = BM / 64;
    __shared__ __align__(16) char smem[2 * BUFSZ];

    const int tid = threadIdx.x;
    const int wave = tid >> 6, lane = tid & 63;
    const int quad = lane >> 4, m16 = lane & 15;
    const int wr = wave >> 1, wc = wave & 1;
    const int z = blockIdx.z;
    const int row0 = z * a_row_batch + blockIdx.y * BM;
    const int col0 = blockIdx.x * 128;

    const int srowA = wave * (16 * JA) + (lane >> 2);
    const int srowB = wave * 32 + (lane >> 2);
    const int scol = (lane & 3) * 8;
    const _Float16* agp = A + (size_t)(row0 + srowA) * lda + scol;
    const _Float16* bgp = B + (size_t)z * b_batch + (size_t)(col0 + srowB) * ldb + scol;
    const int ldsAoff = wave * (1024 * JA);
    const int ldsBoff = BM * 64 + wave * 2048;

    f32x4 acc[MT][4];
#pragma unroll
    for (int mt = 0; mt < MT; ++mt)
#pragma unroll
        for (int nt = 0; nt < 4; ++nt) acc[mt][nt] = (f32x4){0.f, 0.f, 0.f, 0.f};

    const int nIter = K / 32;
    auto stage = [&](int i, int buf) {
        char* base = smem + buf * BUFSZ;
        const int k0 = i * 32;
#pragma unroll
        for (int j = 0; j < JA; ++j)
            glds16(agp + k0 + j * 16 * lda, base + ldsAoff + j * 1024);
#pragma unroll
        for (int j = 0; j < 2; ++j)
            glds16(bgp + k0 + j * 16 * ldb, base + ldsBoff + j * 1024);
    };

    stage(0, 0);
    for (int i = 0; i < nIter; ++i) {
        __syncthreads();
        if (i + 1 < nIter) stage(i + 1, (i + 1) & 1);
        const char* bb = smem + (i & 1) * BUFSZ;
        const char* pa = bb + (wr * (BM / 2) + m16) * 64 + quad * 16;
        const char* pb = bb + BM * 64 + (wc * 64 + m16) * 64 + quad * 16;
        f16x8 af[MT];
#pragma unroll
        for (int mt = 0; mt < MT; ++mt) af[mt] = *(const f16x8*)(pa + mt * 1024);
#pragma unroll
        for (int nt = 0; nt < 4; ++nt) {
            f16x8 bf = *(const f16x8*)(pb + nt * 1024);
#pragma unroll
            for (int mt = 0; mt < MT; ++mt) acc[mt][nt] = MFMA16(af[mt], bf, acc[mt][nt]);
        }
    }

    if (OUT == 0) {
        _Float16* o = (_Float16*)O1;
#pragma unroll
        for (int mt = 0; mt < MT; ++mt)
#pragma unroll
            for (int nt = 0; nt < 4; ++nt)
#pragma unroll
                for (int rr = 0; rr < 4; ++rr) {
                    int row = row0 + wr * (BM / 2) + mt * 16 + quad * 4 + rr;
                    int col = col0 + wc * 64 + nt * 16 + m16;
                    o[(size_t)row * ldo + col] = (_Float16)acc[mt][nt][rr];
                }
    } else {
        _Float16* vtp = (_Float16*)O1;
        const int row0g = blockIdx.y * 128;
        const int b = row0g >> 11;
        const int s_base = (row0g & 2047) + wr * 64;
        char* reg = smem + wave * 4096;
#pragma unroll
        for (int p = 0; p < 2; ++p) {
            __syncthreads();
#pragma unroll
            for (int nt2 = 0; nt2 < 2; ++nt2) {
                int nt = p * 2 + nt2;
#pragma unroll
                for (int mt = 0; mt < 4; ++mt) {
                    f16x4 pk;
#pragma unroll
                    for (int rr = 0; rr < 4; ++rr) pk[rr] = (_Float16)acc[mt][nt][rr];
                    *(f16x4*)(reg + (nt2 * 16 + m16) * 128 + (mt * 16 + quad * 4) * 2) = pk;
                }
            }
            __syncthreads();
            const int u_base = col0 + wc * 64 + p * 32;
#pragma unroll
            for (int j = 0; j < 4; ++j) {
                int n = j * 8 + (lane >> 3);
                int mo = (lane & 7) * 8;
                f16x8 val = *(const f16x8*)(reg + n * 128 + mo * 2);
                *(f16x8*)(vtp + (size_t)(b * 512 + u_base + n) * 2048 + s_base + mo) = val;
            }
        }
    }
}

extern "C" void kernel_launch(void* const* d_in, const int* in_sizes, int n_in,
                              void* d_out, int out_size, void* d_ws, size_t ws_size,
                              hipStream_t stream) {
    const float* enc = (const float*)d_in[0];
    const float* dec = (const float*)d_in[1];
    const float* Wq = (const float*)d_in[2];
    const float* Wk = (const float*)d_in[3];
    const float* Wv = (const float*)d_in[4];
    float* out = (float*)d_out;

    char* ws = (char*)d_ws;
    _Float16* qh = (_Float16*)(ws);
    _Float16* kh = (_Float16*)(ws + ((size_t)8 << 20));
    _Float16* vt = (_Float16*)(ws + ((size_t)32 << 20));
    _Float16* dech = (_Float16*)(ws + ((size_t)48 << 20));
    _Float16* wts = (_Float16*)(ws + ((size_t)56 << 20));
    _Float16* ench = (_Float16*)(ws + ((size_t)112 << 20));

    dim3 blk(256);
    convert_f16<<<4096, blk, 0, stream>>>(enc, ench);
    convert_f16<<<2048, blk, 0, stream>>>(dec, dech);
    wtrans_kernel<<<dim3(8, 8, 3), blk, 0, stream>>>(Wq, Wk, Wv, wts);
    gemm_kernel<64, 0><<<dim3(4, 128, 1), blk, 0, stream>>>(
        dech, wts, qh, 512, 512, 512, 0, 0, 512);
    gemm_kernel<128, 0><<<dim3(4, 128, 1), blk, 0, stream>>>(
        ench, wts + 262144, kh, 512, 512, 512, 0, 0, 512);
    gemm_kernel<128, 1><<<dim3(4, 128, 1), blk, 0, stream>>>(
        ench, wts + 524288, vt, 512, 512, 512, 0, 0, 0);
    attn_kernel<<<256, 512, 0, stream>>>(qh, kh, vt, out);
}

// Round 6
// 246.369 us; speedup vs baseline: 1.5222x; 1.5222x over previous
//
#include <hip/hip_runtime.h>
#include <hip/hip_bf16.h>

// Cross-attention B=8, S_ENC=2048, S_DEC=1024, D=512, U=512.
// R6: revert R5 fusion (barrier-quantum too small: 8 MFMA / 2 barriers, 5.6%
// MfmaUtil). R4 pipeline + occupancy fix for the latency-bound GEMMs:
// PV 64x64 tiles (1024 blocks, 16 waves/CU, was 8), k-proj BM=64 (1024 blocks).
// All fp16 single-MFMA (v_mfma_f32_16x16x32_f16), fp32 accum/logits.
//
// ws (aliased): qh [0,8M) | kh [8M,24M) | P [0,32M) after score | vt [32M,48M)
//   S [48M,112M) fp32 | dech @48M (dead pre-S) | Wt @56M (dead pre-S) | ench @112M

typedef __attribute__((ext_vector_type(8))) _Float16 f16x8;
typedef __attribute__((ext_vector_type(4))) _Float16 f16x4;
typedef __attribute__((ext_vector_type(4))) float f32x4;

#define MFMA16(a, b, c) __builtin_amdgcn_mfma_f32_16x16x32_f16(a, b, c, 0, 0, 0)

__device__ __forceinline__ void glds16(const void* g, void* l) {
    __builtin_amdgcn_global_load_lds(
        (const __attribute__((address_space(1))) void*)g,
        (__attribute__((address_space(3))) void*)l, 16, 0, 0);
}

// fp32[N] -> fp16[N], 8 elems/thread.
__global__ __launch_bounds__(256) void convert_f16(const float* __restrict__ x,
                                                   _Float16* __restrict__ o) {
    size_t i = ((size_t)blockIdx.x * 256 + threadIdx.x) * 8;
    float4 a0 = *(const float4*)(x + i);
    float4 a1 = *(const float4*)(x + i + 4);
    float v[8] = {a0.x, a0.y, a0.z, a0.w, a1.x, a1.y, a1.z, a1.w};
    f16x8 h;
#pragma unroll
    for (int j = 0; j < 8; ++j) h[j] = (_Float16)v[j];
    *(f16x8*)(o + i) = h;
}

// W[512][512] (z selects Wq/Wk/Wv) -> Wt fp16 plane [u][d].
__global__ __launch_bounds__(256) void wtrans_kernel(const float* __restrict__ Wq,
                                                     const float* __restrict__ Wk,
                                                     const float* __restrict__ Wv,
                                                     _Float16* __restrict__ planes) {
    const float* W = blockIdx.z == 0 ? Wq : (blockIdx.z == 1 ? Wk : Wv);
    _Float16* ot = planes + (size_t)blockIdx.z * 262144;
    __shared__ float T[64][65];
    const int d0 = blockIdx.y * 64, u0 = blockIdx.x * 64;
    const int tr = threadIdx.x >> 4, tc = (threadIdx.x & 15) * 4;
#pragma unroll
    for (int j = 0; j < 4; ++j) {
        float4 vv = *(const float4*)(W + (size_t)(d0 + tr + j * 16) * 512 + u0 + tc);
        T[tr + j * 16][tc + 0] = vv.x;
        T[tr + j * 16][tc + 1] = vv.y;
        T[tr + j * 16][tc + 2] = vv.z;
        T[tr + j * 16][tc + 3] = vv.w;
    }
    __syncthreads();
#pragma unroll
    for (int j = 0; j < 4; ++j) {
        int ul = tr + j * 16;
        f16x4 h;
#pragma unroll
        for (int i = 0; i < 4; ++i) h[i] = (_Float16)T[tc + i][ul];
        *(f16x4*)(ot + (size_t)(u0 + ul) * 512 + d0 + tc) = h;
    }
}

// BM x BN tile GEMM, C[m][n] = sum_k A[m][k]*B[n][k] (fp16 in, fp32 accum).
// 4 waves in 2x2; wave tile (BM/2)x(BN/2). Double-buffered LDS, glds-16
// staging (64 B LDS rows), ds_read_b128 frags. One barrier per K-iter.
// OUT: 0 = fp16 C, 1 = transposed fp16 vt[b][u][s] (BM=BN=128 only), 2 = fp32 C.
template <int BM, int BN, int OUT>
__global__ __launch_bounds__(256) void gemm_kernel(
    const _Float16* __restrict__ A, const _Float16* __restrict__ B,
    void* __restrict__ O1,
    int lda, int ldb, int K, int a_row_batch, long b_batch, int ldo) {
    constexpr int ASZ = BM * 64, BSZ = BN * 64;
    constexpr int BUFSZ = ASZ + BSZ;
    constexpr int MT = BM / 32, NT = BN / 32;
    constexpr int JA = BM / 64, JB = BN / 64;
    __shared__ __align__(16) char smem[2 * BUFSZ];

    const int tid = threadIdx.x;
    const int wave = tid >> 6, lane = tid & 63;
    const int quad = lane >> 4, m16 = lane & 15;
    const int wr = wave >> 1, wc = wave & 1;
    const int z = blockIdx.z;
    const int row0 = z * a_row_batch + blockIdx.y * BM;
    const int col0 = blockIdx.x * BN;

    const int srowA = wave * (16 * JA) + (lane >> 2);
    const int srowB = wave * (16 * JB) + (lane >> 2);
    const int scol = (lane & 3) * 8;
    const _Float16* agp = A + (size_t)(row0 + srowA) * lda + scol;
    const _Float16* bgp = B + (size_t)z * b_batch + (size_t)(col0 + srowB) * ldb + scol;
    const int ldsAoff = wave * (1024 * JA);
    const int ldsBoff = ASZ + wave * (1024 * JB);

    f32x4 acc[MT][NT];
#pragma unroll
    for (int mt = 0; mt < MT; ++mt)
#pragma unroll
        for (int nt = 0; nt < NT; ++nt) acc[mt][nt] = (f32x4){0.f, 0.f, 0.f, 0.f};

    const int nIter = K / 32;
    auto stage = [&](int i, int buf) {
        char* base = smem + buf * BUFSZ;
        const int k0 = i * 32;
#pragma unroll
        for (int j = 0; j < JA; ++j)
            glds16(agp + k0 + j * 16 * lda, base + ldsAoff + j * 1024);
#pragma unroll
        for (int j = 0; j < JB; ++j)
            glds16(bgp + k0 + j * 16 * ldb, base + ldsBoff + j * 1024);
    };

    stage(0, 0);
    for (int i = 0; i < nIter; ++i) {
        __syncthreads();
        if (i + 1 < nIter) stage(i + 1, (i + 1) & 1);
        const char* bb = smem + (i & 1) * BUFSZ;
        const char* pa = bb + (wr * (BM / 2) + m16) * 64 + quad * 16;
        const char* pb = bb + ASZ + (wc * (BN / 2) + m16) * 64 + quad * 16;
        f16x8 af[MT];
#pragma unroll
        for (int mt = 0; mt < MT; ++mt) af[mt] = *(const f16x8*)(pa + mt * 1024);
#pragma unroll
        for (int nt = 0; nt < NT; ++nt) {
            f16x8 bf = *(const f16x8*)(pb + nt * 1024);
#pragma unroll
            for (int mt = 0; mt < MT; ++mt) acc[mt][nt] = MFMA16(af[mt], bf, acc[mt][nt]);
        }
    }

    if (OUT == 0) {
        _Float16* o = (_Float16*)O1;
#pragma unroll
        for (int mt = 0; mt < MT; ++mt)
#pragma unroll
            for (int nt = 0; nt < NT; ++nt)
#pragma unroll
                for (int rr = 0; rr < 4; ++rr) {
                    int row = row0 + wr * (BM / 2) + mt * 16 + quad * 4 + rr;
                    int col = col0 + wc * (BN / 2) + nt * 16 + m16;
                    o[(size_t)row * ldo + col] = (_Float16)acc[mt][nt][rr];
                }
    } else if (OUT == 2) {
        float* o = (float*)O1;
#pragma unroll
        for (int mt = 0; mt < MT; ++mt)
#pragma unroll
            for (int nt = 0; nt < NT; ++nt)
#pragma unroll
                for (int rr = 0; rr < 4; ++rr) {
                    int row = row0 + wr * (BM / 2) + mt * 16 + quad * 4 + rr;
                    int col = col0 + wc * (BN / 2) + nt * 16 + m16;
                    o[(size_t)row * ldo + col] = acc[mt][nt][rr];
                }
    } else {
        // OUT == 1 (BM=BN=128): write C^T fp16 into vt[b][u][s], coalesced via
        // per-wave LDS transpose region (4 KB/wave, two passes of 32 n's).
        _Float16* vtp = (_Float16*)O1;
        const int row0g = blockIdx.y * 128;
        const int b = row0g >> 11;
        const int s_base = (row0g & 2047) + wr * 64;
        char* reg = smem + wave * 4096;
#pragma unroll
        for (int p = 0; p < 2; ++p) {
            __syncthreads();
#pragma unroll
            for (int nt2 = 0; nt2 < 2; ++nt2) {
                int nt = p * 2 + nt2;
#pragma unroll
                for (int mt = 0; mt < 4; ++mt) {
                    f16x4 pk;
#pragma unroll
                    for (int rr = 0; rr < 4; ++rr) pk[rr] = (_Float16)acc[mt][nt][rr];
                    *(f16x4*)(reg + (nt2 * 16 + m16) * 128 + (mt * 16 + quad * 4) * 2) = pk;
                }
            }
            __syncthreads();
            const int u_base = col0 + wc * 64 + p * 32;
#pragma unroll
            for (int j = 0; j < 4; ++j) {
                int n = j * 8 + (lane >> 3);
                int mo = (lane & 7) * 8;
                f16x8 val = *(const f16x8*)(reg + n * 128 + mo * 2);
                *(f16x8*)(vtp + (size_t)(b * 512 + u_base + n) * 2048 + s_base + mo) = val;
            }
        }
    }
}

// Row softmax over 2048 cols, fp32 in -> fp16 out. One block per row.
__global__ __launch_bounds__(256) void softmax_kernel(const float* __restrict__ S,
                                                      _Float16* __restrict__ P) {
    const int row = blockIdx.x;
    const int tid = threadIdx.x;
    const int wave = tid >> 6, lane = tid & 63;
    __shared__ float red[8];

    const float* sp = S + (size_t)row * 2048 + tid * 8;
    float4 x0 = *(const float4*)sp;
    float4 x1 = *(const float4*)(sp + 4);
    float v[8] = {x0.x, x0.y, x0.z, x0.w, x1.x, x1.y, x1.z, x1.w};

    float mx = v[0];
#pragma unroll
    for (int i = 1; i < 8; ++i) mx = fmaxf(mx, v[i]);
#pragma unroll
    for (int off = 32; off > 0; off >>= 1) mx = fmaxf(mx, __shfl_down(mx, off));
    if (lane == 0) red[wave] = mx;
    __syncthreads();
    if (tid == 0) red[4] = fmaxf(fmaxf(red[0], red[1]), fmaxf(red[2], red[3]));
    __syncthreads();
    mx = red[4];

    float e[8];
    float sum = 0.f;
#pragma unroll
    for (int i = 0; i < 8; ++i) {
        e[i] = exp2f((v[i] - mx) * 1.44269504088896f);
        sum += e[i];
    }
#pragma unroll
    for (int off = 32; off > 0; off >>= 1) sum += __shfl_down(sum, off);
    if (lane == 0) red[wave] = sum;
    __syncthreads();
    if (tid == 0) red[5] = red[0] + red[1] + red[2] + red[3];
    __syncthreads();
    float inv = 1.0f / red[5];

    f16x8 ov;
#pragma unroll
    for (int i = 0; i < 8; ++i) ov[i] = (_Float16)(e[i] * inv);
    *(f16x8*)(P + (size_t)row * 2048 + tid * 8) = ov;
}

extern "C" void kernel_launch(void* const* d_in, const int* in_sizes, int n_in,
                              void* d_out, int out_size, void* d_ws, size_t ws_size,
                              hipStream_t stream) {
    const float* enc = (const float*)d_in[0];  // [8,2048,512]
    const float* dec = (const float*)d_in[1];  // [8,1024,512]
    const float* Wq = (const float*)d_in[2];   // [512,512]
    const float* Wk = (const float*)d_in[3];
    const float* Wv = (const float*)d_in[4];
    float* out = (float*)d_out;                // [8,1024,512] fp32

    char* ws = (char*)d_ws;
    _Float16* qh = (_Float16*)(ws);
    _Float16* kh = (_Float16*)(ws + ((size_t)8 << 20));
    _Float16* P = (_Float16*)(ws);                          // aliases qh/kh after score
    _Float16* vt = (_Float16*)(ws + ((size_t)32 << 20));
    float* S = (float*)(ws + ((size_t)48 << 20));
    _Float16* dech = (_Float16*)(ws + ((size_t)48 << 20));  // dead before S written
    _Float16* wts = (_Float16*)(ws + ((size_t)56 << 20));   // dead before S written
    _Float16* ench = (_Float16*)(ws + ((size_t)112 << 20));

    dim3 blk(256);
    convert_f16<<<4096, blk, 0, stream>>>(enc, ench);
    convert_f16<<<2048, blk, 0, stream>>>(dec, dech);
    wtrans_kernel<<<dim3(8, 8, 3), blk, 0, stream>>>(Wq, Wk, Wv, wts);
    // Projections
    gemm_kernel<64, 128, 0><<<dim3(4, 128, 1), blk, 0, stream>>>(
        dech, wts, qh, 512, 512, 512, 0, 0, 512);
    gemm_kernel<64, 128, 0><<<dim3(4, 256, 1), blk, 0, stream>>>(
        ench, wts + 262144, kh, 512, 512, 512, 0, 0, 512);
    gemm_kernel<128, 128, 1><<<dim3(4, 128, 1), blk, 0, stream>>>(
        ench, wts + 524288, vt, 512, 512, 512, 0, 0, 0);
    // Score: S[b,q,s] = q . k^T
    gemm_kernel<128, 128, 2><<<dim3(16, 8, 8), blk, 0, stream>>>(
        qh, kh, S, 512, 512, 512, 1024, (long)2048 * 512, 2048);
    softmax_kernel<<<8192, blk, 0, stream>>>(S, P);
    // PV: out[b,q,u] = P . V   (64x64 tiles, 1024 blocks = 4/CU, 16 waves/CU)
    gemm_kernel<64, 64, 2><<<dim3(8, 16, 8), blk, 0, stream>>>(
        P, vt, out, 2048, 2048, 2048, 1024, (long)512 * 2048, 512);
}